// Round 22
// baseline (110.293 us; speedup 1.0000x reference)
//
#include <hip/hip_runtime.h>

// CapsNet forward.
// packAll: w2 -> MFMA B-fragments + W_route -> f16 c-pairs   (R16 proven)
// conv_fused: 2 samples/block, 640 thr. conv1 fp32 (per-thread identical to
//   R16) -> sOut[2][400][20] f16 -> conv2 MFMA over 72 rows = 3 wave-tiles
//   (was 4 per 2 samples) -> u [B][144][8] f32.
// routing2: R21-proven (2 samples/block, 1024 thr, stride-82 u_hat LDS,
//   W 2-deep prefetch, shfl-fused squash).

typedef _Float16 half2_t __attribute__((ext_vector_type(2)));
typedef _Float16 f16x4 __attribute__((ext_vector_type(4)));
typedef _Float16 f16x8 __attribute__((ext_vector_type(8)));
typedef float f32x16 __attribute__((ext_vector_type(16)));

static __device__ __forceinline__ float fdot2f(half2_t a, half2_t b, float c) {
#if __has_builtin(__builtin_amdgcn_fdot2)
  return __builtin_amdgcn_fdot2(a, b, c, false);
#else
  return c + (float)a[0] * (float)b[0] + (float)a[1] * (float)b[1];
#endif
}

static __device__ __forceinline__ half2_t h2(unsigned int u) {
  return __builtin_bit_cast(half2_t, u);
}

static __device__ __forceinline__ unsigned int pkh2(float a, float b) {
  half2_t h;
  h[0] = (_Float16)a;
  h[1] = (_Float16)b;
  return __builtin_bit_cast(unsigned int, h);
}

static __device__ __forceinline__ f32x16 zero16() {
  f32x16 z = {0.f, 0.f, 0.f, 0.f, 0.f, 0.f, 0.f, 0.f,
              0.f, 0.f, 0.f, 0.f, 0.f, 0.f, 0.f, 0.f};
  return z;
}

// Fused packs. idx < 92160: W_route -> wPr f16 c-pairs.
//              idx < 41472: w2 -> wBg MFMA B-fragments.
__global__ __launch_bounds__(256) void packAll(
    const float* __restrict__ w2, const float* __restrict__ Wr,
    _Float16* __restrict__ wBg, unsigned int* __restrict__ wPr) {
  int idx = blockIdx.x * 256 + threadIdx.x;
  if (idx < 92160) {
    int cp = idx & 3;
    int row = idx >> 2;
    const float* src = Wr + (size_t)row * 8 + cp * 2;
    wPr[idx] = pkh2(src[0], src[1]);
  }
  if (idx < 41472) {
    int j = idx & 7;
    int lane = (idx >> 3) & 63;
    int step = idx >> 9;
    int kh = step / 9, kw = step - kh * 9;
    int co = lane & 31, ci = (lane >> 5) * 8 + j;
    wBg[idx] = (_Float16)w2[(co * 16 + ci) * 81 + kh * 9 + kw];
  }
}

// conv_fused: block = 2 samples, 640 threads (10 waves).
// Phase 1: conv1 fp32, thread = (s, co, oh). Phase 2: conv2 MFMA, 3 waves
// cover 72 rows (wave 2 has 8 valid). B-fragments from global (L2).
__global__ __launch_bounds__(640) void conv_fused(
    const float* __restrict__ in, const float* __restrict__ w,
    const float* __restrict__ bias1, const _Float16* __restrict__ wBg,
    const float* __restrict__ bias2, float* __restrict__ u) {
  __shared__ __align__(16) float sIn[1568];      // [2][784]
  __shared__ float sW[1296];                     // 16x81
  __shared__ __align__(16) _Float16 sOut[16000]; // [2][ih*20+iw][20] (16 used)
  int b0 = blockIdx.x * 2, t = threadIdx.x;
  for (int i = t; i < 1568; i += 640) {
    int s = i / 784, k = i - s * 784;
    sIn[i] = in[(size_t)(b0 + s) * 784 + k];
  }
  for (int i = t; i < 1296; i += 640) sW[i] = w[i];
  __syncthreads();
  {
    int s = t / 320, tt = t - s * 320;
    int co = tt / 20, oh = tt % 20;
    float bv = bias1[co];
    float acc[20];
#pragma unroll
    for (int j = 0; j < 20; ++j) acc[j] = bv;
#pragma unroll
    for (int kh = 0; kh < 9; ++kh) {
      float r[28];
      const float4* row = (const float4*)&sIn[s * 784 + (oh + kh) * 28];
#pragma unroll
      for (int q = 0; q < 7; ++q) {
        float4 v = row[q];
        r[q * 4 + 0] = v.x; r[q * 4 + 1] = v.y;
        r[q * 4 + 2] = v.z; r[q * 4 + 3] = v.w;
      }
      const float* wr = &sW[co * 81 + kh * 9];
#pragma unroll
      for (int kw = 0; kw < 9; ++kw) {
        float wv = wr[kw];
#pragma unroll
        for (int j = 0; j < 20; ++j) acc[j] += wv * r[kw + j];
      }
    }
#pragma unroll
    for (int j = 0; j < 20; ++j)
      sOut[s * 8000 + (oh * 20 + j) * 20 + co] = (_Float16)acc[j];
  }
  __syncthreads();

  // ---- conv2 MFMA: waves 0-2 (rows r = wv*32 + l31; valid r < 72) ----
  int wv = t >> 6, lane = t & 63;
  if (wv < 3) {
    int l31 = lane & 31, half = lane >> 5;
    int r = wv * 32 + l31;
    int rc = (r < 72) ? r : 71;
    int s = rc / 36, pos = rc - s * 36;
    int oh = pos / 6, ow = pos - oh * 6;
    int tb = s * 8000 + (oh * 40 + ow * 2) * 20 + half * 8;
    f32x16 acc = zero16();
    for (int kh = 0; kh < 9; ++kh) {
      int abase = tb + kh * 400;   // (kh*20)*20
#pragma unroll
      for (int kw = 0; kw < 9; ++kw) {
        f16x8 bf = *(const f16x8*)(wBg + ((kh * 9 + kw) * 64 + lane) * 8);
        const _Float16* ap = sOut + abase + kw * 20;
        f16x4 lo = *(const f16x4*)ap;
        f16x4 hi = *(const f16x4*)(ap + 4);
        f16x8 a = __builtin_shufflevector(lo, hi, 0, 1, 2, 3, 4, 5, 6, 7);
        acc = __builtin_amdgcn_mfma_f32_32x32x16_f16(a, bf, acc, 0, 0, 0);
      }
    }
    float bv = bias2[l31];
    int c8 = l31 >> 2;
    int ibco = (l31 & 3) * 36;
#pragma unroll
    for (int reg = 0; reg < 16; ++reg) {
      int rr = wv * 32 + (reg & 3) + 8 * (reg >> 2) + 4 * half;
      if (rr < 72) {
        int s2 = rr / 36, pos2 = rr - s2 * 36;
        u[(size_t)(b0 + s2) * 1152 + (ibco + pos2) * 8 + c8] = acc[reg] + bv;
      }
    }
  }
}

// routing2: block = 2 samples, 1024 threads. u_hat f16 in LDS (stride 82);
// W streamed from L2 once per block with 2-deep prefetch. Squash via
// 16-lane shfl butterfly fused into the s-reduce phase.  (R21 proven)
__global__ __launch_bounds__(1024) void routing2_kernel(
    const float* __restrict__ u, const unsigned int* __restrict__ wPr,
    float* __restrict__ out, int B) {
  __shared__ unsigned int uhh[2][11808];   // [sl][i*82+dp] f16 d-pairs (80 used)
  __shared__ unsigned int ush[2][576];     // u f16 c-pairs [i][4]
  __shared__ float blog[2][1440];
  __shared__ float cc[2][1440];
  __shared__ float spart[2][960];          // [sl][ch 6][160]
  __shared__ float vv[2][160];
  __shared__ unsigned int vvh[2][80];
  int b0 = blockIdx.x * 2, t = threadIdx.x;
  for (int j = t; j < 1152; j += 1024) {
    int sl2 = j / 576, k = j - sl2 * 576;
    float2 p = *(const float2*)(u + (size_t)(b0 + sl2) * 1152 + k * 2);
    ush[sl2][k] = pkh2(p.x, p.y);
  }
  for (int j = t; j < 2880; j += 1024) blog[j / 1440][j % 1440] = 0.f;
  __syncthreads();

  // ---- u_hat with 2-deep W prefetch ----
  {
    const uint4* W4 = (const uint4*)wPr;   // rows [i*160+o*16+d] of 8 f16
    int idx = t;
    bool valid = idx < 11520;
    int i_ = 0, dp_ = 0;
    uint4 w0a, w1a;
    if (valid) {
      i_ = idx / 80; dp_ = idx - i_ * 80;
      int row = i_ * 160 + (dp_ >> 3) * 16 + (dp_ & 7) * 2;
      w0a = W4[row]; w1a = W4[row + 1];
    }
    while (valid) {
      int nidx = idx + 1024;
      bool nvalid = nidx < 11520;
      int ni = 0, ndp = 0;
      uint4 w0b, w1b;
      if (nvalid) {
        ni = nidx / 80; ndp = nidx - ni * 80;
        int nrow = ni * 160 + (ndp >> 3) * 16 + (ndp & 7) * 2;
        w0b = W4[nrow]; w1b = W4[nrow + 1];
      }
#pragma unroll
      for (int sl2 = 0; sl2 < 2; ++sl2) {
        const uint2* up = (const uint2*)&ush[sl2][i_ * 4];
        uint2 ua = up[0], ub = up[1];
        half2_t u0 = h2(ua.x), u1 = h2(ua.y), u2 = h2(ub.x), u3 = h2(ub.y);
        float a0 = fdot2f(h2(w0a.x), u0,
                   fdot2f(h2(w0a.y), u1,
                   fdot2f(h2(w0a.z), u2, fdot2f(h2(w0a.w), u3, 0.f))));
        float a1 = fdot2f(h2(w1a.x), u0,
                   fdot2f(h2(w1a.y), u1,
                   fdot2f(h2(w1a.z), u2, fdot2f(h2(w1a.w), u3, 0.f))));
        uhh[sl2][i_ * 82 + dp_] = pkh2(a0, a1);
      }
      idx = nidx; i_ = ni; dp_ = ndp;
      w0a = w0b; w1a = w1b;
      valid = nvalid;
    }
  }
  __syncthreads();

  int sl = t >> 9, tl = t & 511;
  for (int it = 0; it < 3; ++it) {
    if (it > 0) {
      if (tl < 144) {
        const float* br = &blog[sl][tl * 10];
        float mx = br[0];
#pragma unroll
        for (int o = 1; o < 10; ++o) mx = fmaxf(mx, br[o]);
        float e[10];
        float sum = 0.f;
#pragma unroll
        for (int o = 0; o < 10; ++o) { e[o] = __expf(br[o] - mx); sum += e[o]; }
        float inv = 1.0f / sum;
#pragma unroll
        for (int o = 0; o < 10; ++o) cc[sl][tl * 10 + o] = e[o] * inv;
      }
      __syncthreads();
    }
    // s partials: per sample, 480 lanes = 6 i-chunks x 80 d-pairs
    if (tl < 480) {
      int ch = tl / 80, dp = tl - ch * 80;
      int o = dp >> 3;
      float a0 = 0.f, a1 = 0.f;
      int i0 = ch * 24;
      if (it == 0) {
        for (int i = i0; i < i0 + 24; ++i) {
          half2_t h = h2(uhh[sl][i * 82 + dp]);
          a0 += (float)h[0]; a1 += (float)h[1];
        }
      } else {
        for (int i = i0; i < i0 + 24; ++i) {
          float c = cc[sl][i * 10 + o];
          half2_t h = h2(uhh[sl][i * 82 + dp]);
          a0 += c * (float)h[0]; a1 += c * (float)h[1];
        }
      }
      spart[sl][ch * 160 + dp * 2] = a0;
      spart[sl][ch * 160 + dp * 2 + 1] = a1;
    }
    __syncthreads();
    // fused s-reduce + squash: lanes tl<160 hold s[o=tl/16][d=tl%16]
    if (tl < 160) {
      float s = 0.f;
#pragma unroll
      for (int ch = 0; ch < 6; ++ch) s += spart[sl][ch * 160 + tl];
      if (it == 0) s *= 0.1f;   // softmax of zeros
      float sq = s * s;
      sq += __shfl_xor(sq, 1);
      sq += __shfl_xor(sq, 2);
      sq += __shfl_xor(sq, 4);
      sq += __shfl_xor(sq, 8);
      float coef = (sq / (1.0f + sq)) / sqrtf(sq + 1e-8f);
      float v = coef * s;
      vv[sl][tl] = v;
      float vn = __shfl_xor(v, 1);
      if ((tl & 1) == 0) vvh[sl][tl >> 1] = pkh2(v, vn);
      if (it == 2 && (tl & 15) == 0)
        out[(b0 + sl) * 10 + (tl >> 4)] = coef * sqrtf(sq);   // pred = ||v||
    }
    __syncthreads();
    if (it < 2) {
      for (int idx = t; idx < 2880; idx += 1024) {
        int s2 = idx / 1440, r = idx - s2 * 1440;
        int i = r / 10, o = r - i * 10;
        const uint2* uhp = (const uint2*)&uhh[s2][i * 82 + o * 8];
        const uint2* vp = (const uint2*)&vvh[s2][o * 8];
        float dot = 0.f;
#pragma unroll
        for (int q = 0; q < 4; ++q) {
          uint2 A = uhp[q], V = vp[q];
          dot = fdot2f(h2(A.x), h2(V.x), fdot2f(h2(A.y), h2(V.y), dot));
        }
        blog[s2][r] += dot;
      }
      __syncthreads();
    }
  }
  if (tl < 160) out[B * 10 + (b0 + sl) * 160 + tl] = vv[sl][tl];
}

extern "C" void kernel_launch(void* const* d_in, const int* in_sizes, int n_in,
                              void* d_out, int out_size, void* d_ws, size_t ws_size,
                              hipStream_t stream) {
  const float* in = (const float*)d_in[0];
  const float* w1 = (const float*)d_in[1];
  const float* b1 = (const float*)d_in[2];
  const float* w2 = (const float*)d_in[3];
  const float* b2 = (const float*)d_in[4];
  const float* Wr = (const float*)d_in[5];
  float* out = (float*)d_out;
  int B = in_sizes[0] / 784;
  float* wsf = (float*)d_ws;

  float* u = wsf;                                    // [B][1152] f32
  float* tail = wsf + (size_t)B * 1152;
  _Float16* wBg = (_Float16*)tail;                   // 41472 f16 = 20736 f
  unsigned int* wPr = (unsigned int*)(tail + 20736); // 92160 dw

  packAll<<<360, 256, 0, stream>>>(w2, Wr, wBg, wPr);
  conv_fused<<<B / 2, 640, 0, stream>>>(in, w1, b1, wBg, b2, u);
  routing2_kernel<<<B / 2, 1024, 0, stream>>>(u, wPr, out, B);
}

// Round 23
// 102.665 us; speedup vs baseline: 1.0743x; 1.0743x over previous
//
#include <hip/hip_runtime.h>

// CapsNet forward.
// packAll: w2 -> MFMA B-fragments + W_route -> f16 c-pairs   (R16 proven)
// conv_fused: conv1 fp32 -> sOut LDS -> conv2 MFMA -> u f32   (R16/R21 proven)
// routing2: R21 structure + register-resident b: lane (sl,i) (t<288) owns
//   b[10] in VGPRs; b-update is barrier-free; softmax reads registers; blog
//   LDS array deleted. 3 barriers/iter (was 4).

typedef _Float16 half2_t __attribute__((ext_vector_type(2)));
typedef _Float16 f16x4 __attribute__((ext_vector_type(4)));
typedef _Float16 f16x8 __attribute__((ext_vector_type(8)));
typedef float f32x16 __attribute__((ext_vector_type(16)));

static __device__ __forceinline__ float fdot2f(half2_t a, half2_t b, float c) {
#if __has_builtin(__builtin_amdgcn_fdot2)
  return __builtin_amdgcn_fdot2(a, b, c, false);
#else
  return c + (float)a[0] * (float)b[0] + (float)a[1] * (float)b[1];
#endif
}

static __device__ __forceinline__ half2_t h2(unsigned int u) {
  return __builtin_bit_cast(half2_t, u);
}

static __device__ __forceinline__ unsigned int pkh2(float a, float b) {
  half2_t h;
  h[0] = (_Float16)a;
  h[1] = (_Float16)b;
  return __builtin_bit_cast(unsigned int, h);
}

static __device__ __forceinline__ f32x16 zero16() {
  f32x16 z = {0.f, 0.f, 0.f, 0.f, 0.f, 0.f, 0.f, 0.f,
              0.f, 0.f, 0.f, 0.f, 0.f, 0.f, 0.f, 0.f};
  return z;
}

// Fused packs. idx < 92160: W_route -> wPr f16 c-pairs.
//              idx < 41472: w2 -> wBg MFMA B-fragments.
__global__ __launch_bounds__(256) void packAll(
    const float* __restrict__ w2, const float* __restrict__ Wr,
    _Float16* __restrict__ wBg, unsigned int* __restrict__ wPr) {
  int idx = blockIdx.x * 256 + threadIdx.x;
  if (idx < 92160) {
    int cp = idx & 3;
    int row = idx >> 2;
    const float* src = Wr + (size_t)row * 8 + cp * 2;
    wPr[idx] = pkh2(src[0], src[1]);
  }
  if (idx < 41472) {
    int j = idx & 7;
    int lane = (idx >> 3) & 63;
    int step = idx >> 9;
    int kh = step / 9, kw = step - kh * 9;
    int co = lane & 31, ci = (lane >> 5) * 8 + j;
    wBg[idx] = (_Float16)w2[(co * 16 + ci) * 81 + kh * 9 + kw];
  }
}

// conv_fused: block = 1 sample, 320 threads (5 waves). (R16/R21 proven)
__global__ __launch_bounds__(320) void conv_fused(
    const float* __restrict__ in, const float* __restrict__ w,
    const float* __restrict__ bias1, const _Float16* __restrict__ wBg,
    const float* __restrict__ bias2, float* __restrict__ u) {
  __shared__ __align__(16) float sIn[784];      // 28x28
  __shared__ float sW[1296];                    // 16x81
  __shared__ __align__(16) _Float16 sOut[8000]; // [ih*20+iw][20] (16 used)
  int b = blockIdx.x, t = threadIdx.x;
  const float* inb = in + b * 784;
  for (int i = t; i < 784; i += 320) sIn[i] = inb[i];
  for (int i = t; i < 1296; i += 320) sW[i] = w[i];
  __syncthreads();
  {
    int co = t / 20, oh = t % 20;   // 16*20 = 320 work items
    float bv = bias1[co];
    float acc[20];
#pragma unroll
    for (int j = 0; j < 20; ++j) acc[j] = bv;
#pragma unroll
    for (int kh = 0; kh < 9; ++kh) {
      float r[28];
      const float4* row = (const float4*)&sIn[(oh + kh) * 28];
#pragma unroll
      for (int q = 0; q < 7; ++q) {
        float4 v = row[q];
        r[q * 4 + 0] = v.x; r[q * 4 + 1] = v.y; r[q * 4 + 2] = v.z; r[q * 4 + 3] = v.w;
      }
      const float* wr = &sW[co * 81 + kh * 9];
#pragma unroll
      for (int kw = 0; kw < 9; ++kw) {
        float wv = wr[kw];
#pragma unroll
        for (int j = 0; j < 20; ++j) acc[j] += wv * r[kw + j];
      }
    }
#pragma unroll
    for (int j = 0; j < 20; ++j) sOut[(oh * 20 + j) * 20 + co] = (_Float16)acc[j];
  }
  __syncthreads();

  // ---- conv2 MFMA: waves 0-1 (rows r = wv*32 + l31; valid r < 36) ----
  int wv = t >> 6, lane = t & 63;
  if (wv < 2) {
    int l31 = lane & 31, half = lane >> 5;
    int r = wv * 32 + l31;
    int rc = (r < 36) ? r : 35;
    int oh = rc / 6, ow = rc - oh * 6;
    int tb = (oh * 40 + ow * 2) * 20 + half * 8;
    f32x16 acc = zero16();
    for (int kh = 0; kh < 9; ++kh) {
      int abase = tb + kh * 400;   // (kh*20)*20
#pragma unroll
      for (int kw = 0; kw < 9; ++kw) {
        f16x8 bf = *(const f16x8*)(wBg + ((kh * 9 + kw) * 64 + lane) * 8);
        const _Float16* ap = sOut + abase + kw * 20;
        f16x4 lo = *(const f16x4*)ap;
        f16x4 hi = *(const f16x4*)(ap + 4);
        f16x8 a = __builtin_shufflevector(lo, hi, 0, 1, 2, 3, 4, 5, 6, 7);
        acc = __builtin_amdgcn_mfma_f32_32x32x16_f16(a, bf, acc, 0, 0, 0);
      }
    }
    float bv = bias2[l31];
    int c8 = l31 >> 2;
    int ibco = (l31 & 3) * 36;
    float* ub = u + (size_t)b * 1152;
#pragma unroll
    for (int reg = 0; reg < 16; ++reg) {
      int rr = wv * 32 + (reg & 3) + 8 * (reg >> 2) + 4 * half;
      if (rr < 36) ub[(ibco + rr) * 8 + c8] = acc[reg] + bv;
    }
  }
}

// routing2: block = 2 samples, 1024 threads. u_hat f16 in LDS (stride 82);
// W 2-deep prefetch; shfl-fused squash; b in registers on lanes t<288.
__global__ __launch_bounds__(1024) void routing2_kernel(
    const float* __restrict__ u, const unsigned int* __restrict__ wPr,
    float* __restrict__ out, int B) {
  __shared__ unsigned int uhh[2][11808];   // [sl][i*82+dp] f16 d-pairs (80 used)
  __shared__ unsigned int ush[2][576];     // u f16 c-pairs [i][4]
  __shared__ float cc[2][1440];
  __shared__ float spart[2][960];          // [sl][ch 6][160]
  __shared__ float vv[2][160];
  __shared__ unsigned int vvh[2][80];
  int b0 = blockIdx.x * 2, t = threadIdx.x;
  for (int j = t; j < 1152; j += 1024) {
    int sl2 = j / 576, k = j - sl2 * 576;
    float2 p = *(const float2*)(u + (size_t)(b0 + sl2) * 1152 + k * 2);
    ush[sl2][k] = pkh2(p.x, p.y);
  }
  __syncthreads();

  // ---- u_hat with 2-deep W prefetch ----
  {
    const uint4* W4 = (const uint4*)wPr;   // rows [i*160+o*16+d] of 8 f16
    int idx = t;
    bool valid = idx < 11520;
    int i_ = 0, dp_ = 0;
    uint4 w0a, w1a;
    if (valid) {
      i_ = idx / 80; dp_ = idx - i_ * 80;
      int row = i_ * 160 + (dp_ >> 3) * 16 + (dp_ & 7) * 2;
      w0a = W4[row]; w1a = W4[row + 1];
    }
    while (valid) {
      int nidx = idx + 1024;
      bool nvalid = nidx < 11520;
      int ni = 0, ndp = 0;
      uint4 w0b, w1b;
      if (nvalid) {
        ni = nidx / 80; ndp = nidx - ni * 80;
        int nrow = ni * 160 + (ndp >> 3) * 16 + (ndp & 7) * 2;
        w0b = W4[nrow]; w1b = W4[nrow + 1];
      }
#pragma unroll
      for (int sl2 = 0; sl2 < 2; ++sl2) {
        const uint2* up = (const uint2*)&ush[sl2][i_ * 4];
        uint2 ua = up[0], ub = up[1];
        half2_t u0 = h2(ua.x), u1 = h2(ua.y), u2 = h2(ub.x), u3 = h2(ub.y);
        float a0 = fdot2f(h2(w0a.x), u0,
                   fdot2f(h2(w0a.y), u1,
                   fdot2f(h2(w0a.z), u2, fdot2f(h2(w0a.w), u3, 0.f))));
        float a1 = fdot2f(h2(w1a.x), u0,
                   fdot2f(h2(w1a.y), u1,
                   fdot2f(h2(w1a.z), u2, fdot2f(h2(w1a.w), u3, 0.f))));
        uhh[sl2][i_ * 82 + dp_] = pkh2(a0, a1);
      }
      idx = nidx; i_ = ni; dp_ = ndp;
      w0a = w0b; w1a = w1b;
      valid = nvalid;
    }
  }
  __syncthreads();

  int sl = t >> 9, tl = t & 511;
  bool bown = t < 288;
  int slb = t / 144, ib = t - (t / 144) * 144;   // valid when bown
  float breg[10];
#pragma unroll
  for (int o = 0; o < 10; ++o) breg[o] = 0.f;

  for (int it = 0; it < 3; ++it) {
    if (it > 0) {
      if (bown) {   // softmax from register b -> cc
        float mx = breg[0];
#pragma unroll
        for (int o = 1; o < 10; ++o) mx = fmaxf(mx, breg[o]);
        float e[10];
        float sum = 0.f;
#pragma unroll
        for (int o = 0; o < 10; ++o) { e[o] = __expf(breg[o] - mx); sum += e[o]; }
        float inv = 1.0f / sum;
#pragma unroll
        for (int o = 0; o < 10; ++o) cc[slb][ib * 10 + o] = e[o] * inv;
      }
      __syncthreads();
    }
    // s partials: per sample, 480 lanes = 6 i-chunks x 80 d-pairs
    if (tl < 480) {
      int ch = tl / 80, dp = tl - ch * 80;
      int o = dp >> 3;
      float a0 = 0.f, a1 = 0.f;
      int i0 = ch * 24;
      if (it == 0) {
        for (int i = i0; i < i0 + 24; ++i) {
          half2_t h = h2(uhh[sl][i * 82 + dp]);
          a0 += (float)h[0]; a1 += (float)h[1];
        }
      } else {
        for (int i = i0; i < i0 + 24; ++i) {
          float c = cc[sl][i * 10 + o];
          half2_t h = h2(uhh[sl][i * 82 + dp]);
          a0 += c * (float)h[0]; a1 += c * (float)h[1];
        }
      }
      spart[sl][ch * 160 + dp * 2] = a0;
      spart[sl][ch * 160 + dp * 2 + 1] = a1;
    }
    __syncthreads();
    // fused s-reduce + squash: lanes tl<160 hold s[o=tl/16][d=tl%16]
    if (tl < 160) {
      float s = 0.f;
#pragma unroll
      for (int ch = 0; ch < 6; ++ch) s += spart[sl][ch * 160 + tl];
      if (it == 0) s *= 0.1f;   // softmax of zeros
      float sq = s * s;
      sq += __shfl_xor(sq, 1);
      sq += __shfl_xor(sq, 2);
      sq += __shfl_xor(sq, 4);
      sq += __shfl_xor(sq, 8);
      float coef = (sq / (1.0f + sq)) / sqrtf(sq + 1e-8f);
      float v = coef * s;
      vv[sl][tl] = v;
      float vn = __shfl_xor(v, 1);
      if ((tl & 1) == 0) vvh[sl][tl >> 1] = pkh2(v, vn);
      if (it == 2 && (tl & 15) == 0)
        out[(b0 + sl) * 10 + (tl >> 4)] = coef * sqrtf(sq);   // pred = ||v||
    }
    __syncthreads();   // vvh ready (and vv for final store)
    // b-update: register accumulation on owner lanes; NO barrier needed after
    if (it < 2 && bown) {
      const uint2* row = (const uint2*)&uhh[slb][ib * 82];
      const uint2* vp = (const uint2*)&vvh[slb][0];
#pragma unroll
      for (int o = 0; o < 10; ++o) {
        uint2 A0 = row[o * 4 + 0], A1 = row[o * 4 + 1];
        uint2 A2 = row[o * 4 + 2], A3 = row[o * 4 + 3];
        uint2 V0 = vp[o * 4 + 0], V1 = vp[o * 4 + 1];
        uint2 V2 = vp[o * 4 + 2], V3 = vp[o * 4 + 3];
        float da = fdot2f(h2(A0.x), h2(V0.x), fdot2f(h2(A0.y), h2(V0.y), 0.f));
        float db = fdot2f(h2(A1.x), h2(V1.x), fdot2f(h2(A1.y), h2(V1.y), 0.f));
        da = fdot2f(h2(A2.x), h2(V2.x), fdot2f(h2(A2.y), h2(V2.y), da));
        db = fdot2f(h2(A3.x), h2(V3.x), fdot2f(h2(A3.y), h2(V3.y), db));
        breg[o] += da + db;
      }
    }
  }
  if (tl < 160) out[B * 10 + (b0 + sl) * 160 + tl] = vv[sl][tl];
}

extern "C" void kernel_launch(void* const* d_in, const int* in_sizes, int n_in,
                              void* d_out, int out_size, void* d_ws, size_t ws_size,
                              hipStream_t stream) {
  const float* in = (const float*)d_in[0];
  const float* w1 = (const float*)d_in[1];
  const float* b1 = (const float*)d_in[2];
  const float* w2 = (const float*)d_in[3];
  const float* b2 = (const float*)d_in[4];
  const float* Wr = (const float*)d_in[5];
  float* out = (float*)d_out;
  int B = in_sizes[0] / 784;
  float* wsf = (float*)d_ws;

  float* u = wsf;                                    // [B][1152] f32
  float* tail = wsf + (size_t)B * 1152;
  _Float16* wBg = (_Float16*)tail;                   // 41472 f16 = 20736 f
  unsigned int* wPr = (unsigned int*)(tail + 20736); // 92160 dw

  packAll<<<360, 256, 0, stream>>>(w2, Wr, wBg, wPr);
  conv_fused<<<B, 320, 0, stream>>>(in, w1, b1, wBg, b2, u);
  routing2_kernel<<<B / 2, 1024, 0, stream>>>(u, wPr, out, B);
}

// Round 24
// 93.865 us; speedup vs baseline: 1.1750x; 1.0938x over previous
//
#include <hip/hip_runtime.h>

// CapsNet forward.
// packAll: w2 -> MFMA B-fragments + W_route -> f16 c-pairs   (R16 proven)
// conv_fused: conv1 fp32 -> sOut LDS -> conv2 MFMA -> u f32   (R16/R21 proven)
// routing2: R23 structure + fixed-dp u_hat phase that ALSO accumulates the
//   it=0 s-partials in registers (deletes the it=0 s-partial phase+barrier).
//   b in registers (R23), shfl-fused squash (R21), stride-82 u_hat LDS.

typedef _Float16 half2_t __attribute__((ext_vector_type(2)));
typedef _Float16 f16x4 __attribute__((ext_vector_type(4)));
typedef _Float16 f16x8 __attribute__((ext_vector_type(8)));
typedef float f32x16 __attribute__((ext_vector_type(16)));

static __device__ __forceinline__ float fdot2f(half2_t a, half2_t b, float c) {
#if __has_builtin(__builtin_amdgcn_fdot2)
  return __builtin_amdgcn_fdot2(a, b, c, false);
#else
  return c + (float)a[0] * (float)b[0] + (float)a[1] * (float)b[1];
#endif
}

static __device__ __forceinline__ half2_t h2(unsigned int u) {
  return __builtin_bit_cast(half2_t, u);
}

static __device__ __forceinline__ unsigned int pkh2(float a, float b) {
  half2_t h;
  h[0] = (_Float16)a;
  h[1] = (_Float16)b;
  return __builtin_bit_cast(unsigned int, h);
}

static __device__ __forceinline__ f32x16 zero16() {
  f32x16 z = {0.f, 0.f, 0.f, 0.f, 0.f, 0.f, 0.f, 0.f,
              0.f, 0.f, 0.f, 0.f, 0.f, 0.f, 0.f, 0.f};
  return z;
}

// Fused packs. idx < 92160: W_route -> wPr f16 c-pairs.
//              idx < 41472: w2 -> wBg MFMA B-fragments.
__global__ __launch_bounds__(256) void packAll(
    const float* __restrict__ w2, const float* __restrict__ Wr,
    _Float16* __restrict__ wBg, unsigned int* __restrict__ wPr) {
  int idx = blockIdx.x * 256 + threadIdx.x;
  if (idx < 92160) {
    int cp = idx & 3;
    int row = idx >> 2;
    const float* src = Wr + (size_t)row * 8 + cp * 2;
    wPr[idx] = pkh2(src[0], src[1]);
  }
  if (idx < 41472) {
    int j = idx & 7;
    int lane = (idx >> 3) & 63;
    int step = idx >> 9;
    int kh = step / 9, kw = step - kh * 9;
    int co = lane & 31, ci = (lane >> 5) * 8 + j;
    wBg[idx] = (_Float16)w2[(co * 16 + ci) * 81 + kh * 9 + kw];
  }
}

// conv_fused: block = 1 sample, 320 threads (5 waves). (R16/R21 proven)
__global__ __launch_bounds__(320) void conv_fused(
    const float* __restrict__ in, const float* __restrict__ w,
    const float* __restrict__ bias1, const _Float16* __restrict__ wBg,
    const float* __restrict__ bias2, float* __restrict__ u) {
  __shared__ __align__(16) float sIn[784];      // 28x28
  __shared__ float sW[1296];                    // 16x81
  __shared__ __align__(16) _Float16 sOut[8000]; // [ih*20+iw][20] (16 used)
  int b = blockIdx.x, t = threadIdx.x;
  const float* inb = in + b * 784;
  for (int i = t; i < 784; i += 320) sIn[i] = inb[i];
  for (int i = t; i < 1296; i += 320) sW[i] = w[i];
  __syncthreads();
  {
    int co = t / 20, oh = t % 20;   // 16*20 = 320 work items
    float bv = bias1[co];
    float acc[20];
#pragma unroll
    for (int j = 0; j < 20; ++j) acc[j] = bv;
#pragma unroll
    for (int kh = 0; kh < 9; ++kh) {
      float r[28];
      const float4* row = (const float4*)&sIn[(oh + kh) * 28];
#pragma unroll
      for (int q = 0; q < 7; ++q) {
        float4 v = row[q];
        r[q * 4 + 0] = v.x; r[q * 4 + 1] = v.y; r[q * 4 + 2] = v.z; r[q * 4 + 3] = v.w;
      }
      const float* wr = &sW[co * 81 + kh * 9];
#pragma unroll
      for (int kw = 0; kw < 9; ++kw) {
        float wv = wr[kw];
#pragma unroll
        for (int j = 0; j < 20; ++j) acc[j] += wv * r[kw + j];
      }
    }
#pragma unroll
    for (int j = 0; j < 20; ++j) sOut[(oh * 20 + j) * 20 + co] = (_Float16)acc[j];
  }
  __syncthreads();

  // ---- conv2 MFMA: waves 0-1 (rows r = wv*32 + l31; valid r < 36) ----
  int wv = t >> 6, lane = t & 63;
  if (wv < 2) {
    int l31 = lane & 31, half = lane >> 5;
    int r = wv * 32 + l31;
    int rc = (r < 36) ? r : 35;
    int oh = rc / 6, ow = rc - oh * 6;
    int tb = (oh * 40 + ow * 2) * 20 + half * 8;
    f32x16 acc = zero16();
    for (int kh = 0; kh < 9; ++kh) {
      int abase = tb + kh * 400;   // (kh*20)*20
#pragma unroll
      for (int kw = 0; kw < 9; ++kw) {
        f16x8 bf = *(const f16x8*)(wBg + ((kh * 9 + kw) * 64 + lane) * 8);
        const _Float16* ap = sOut + abase + kw * 20;
        f16x4 lo = *(const f16x4*)ap;
        f16x4 hi = *(const f16x4*)(ap + 4);
        f16x8 a = __builtin_shufflevector(lo, hi, 0, 1, 2, 3, 4, 5, 6, 7);
        acc = __builtin_amdgcn_mfma_f32_32x32x16_f16(a, bf, acc, 0, 0, 0);
      }
    }
    float bv = bias2[l31];
    int c8 = l31 >> 2;
    int ibco = (l31 & 3) * 36;
    float* ub = u + (size_t)b * 1152;
#pragma unroll
    for (int reg = 0; reg < 16; ++reg) {
      int rr = wv * 32 + (reg & 3) + 8 * (reg >> 2) + 4 * half;
      if (rr < 36) ub[(ibco + rr) * 8 + c8] = acc[reg] + bv;
    }
  }
}

// routing2: block = 2 samples, 1024 threads. Fixed-dp u_hat (960 lanes =
// 12 chunks x 80 dp, 12 i each) with fused it=0 s-accumulation; b in regs.
__global__ __launch_bounds__(1024) void routing2_kernel(
    const float* __restrict__ u, const unsigned int* __restrict__ wPr,
    float* __restrict__ out, int B) {
  __shared__ unsigned int uhh[2][11808];   // [sl][i*82+dp] f16 d-pairs (80 used)
  __shared__ unsigned int ush[2][576];     // u f16 c-pairs [i][4]
  __shared__ float cc[2][1440];
  __shared__ float spart[2][12][160];      // [sl][ch][dp*2+c]
  __shared__ float vv[2][160];
  __shared__ unsigned int vvh[2][80];
  int b0 = blockIdx.x * 2, t = threadIdx.x;
  for (int j = t; j < 1152; j += 1024) {
    int sl2 = j / 576, k = j - sl2 * 576;
    float2 p = *(const float2*)(u + (size_t)(b0 + sl2) * 1152 + k * 2);
    ush[sl2][k] = pkh2(p.x, p.y);
  }
  __syncthreads();

  // ---- u_hat: fixed dp per thread, 12 i's, 2-deep W prefetch.
  //      Also accumulates the it=0 s-partials (softmax(0) => plain sum). ----
  bool act = t < 960;
  int chf = t / 80, dpf = t - (t / 80) * 80;   // chf<12, dpf<80 when act
  if (act) {
    const uint4* W4 = (const uint4*)wPr;   // rows [i*160+o*16+d] of 8 f16
    int rowoff = (dpf >> 3) * 16 + (dpf & 7) * 2;
    int ibase = chf * 12;
    float sA0 = 0.f, sA1 = 0.f, sB0 = 0.f, sB1 = 0.f;
    uint4 w0a = W4[ibase * 160 + rowoff];
    uint4 w1a = W4[ibase * 160 + rowoff + 1];
#pragma unroll
    for (int e = 0; e < 12; ++e) {
      int i = ibase + e;
      uint4 w0b, w1b;
      if (e < 11) {
        w0b = W4[(i + 1) * 160 + rowoff];
        w1b = W4[(i + 1) * 160 + rowoff + 1];
      }
      {
        const uint2* up = (const uint2*)&ush[0][i * 4];
        uint2 ua = up[0], ub = up[1];
        half2_t u0 = h2(ua.x), u1 = h2(ua.y), u2 = h2(ub.x), u3 = h2(ub.y);
        float a0 = fdot2f(h2(w0a.x), u0,
                   fdot2f(h2(w0a.y), u1,
                   fdot2f(h2(w0a.z), u2, fdot2f(h2(w0a.w), u3, 0.f))));
        float a1 = fdot2f(h2(w1a.x), u0,
                   fdot2f(h2(w1a.y), u1,
                   fdot2f(h2(w1a.z), u2, fdot2f(h2(w1a.w), u3, 0.f))));
        uhh[0][i * 82 + dpf] = pkh2(a0, a1);
        sA0 += a0; sA1 += a1;
      }
      {
        const uint2* up = (const uint2*)&ush[1][i * 4];
        uint2 ua = up[0], ub = up[1];
        half2_t u0 = h2(ua.x), u1 = h2(ua.y), u2 = h2(ub.x), u3 = h2(ub.y);
        float a0 = fdot2f(h2(w0a.x), u0,
                   fdot2f(h2(w0a.y), u1,
                   fdot2f(h2(w0a.z), u2, fdot2f(h2(w0a.w), u3, 0.f))));
        float a1 = fdot2f(h2(w1a.x), u0,
                   fdot2f(h2(w1a.y), u1,
                   fdot2f(h2(w1a.z), u2, fdot2f(h2(w1a.w), u3, 0.f))));
        uhh[1][i * 82 + dpf] = pkh2(a0, a1);
        sB0 += a0; sB1 += a1;
      }
      w0a = w0b; w1a = w1b;
    }
    spart[0][chf][dpf * 2] = sA0;
    spart[0][chf][dpf * 2 + 1] = sA1;
    spart[1][chf][dpf * 2] = sB0;
    spart[1][chf][dpf * 2 + 1] = sB1;
  }
  __syncthreads();

  int sl = t >> 9, tl = t & 511;
  bool bown = t < 288;
  int slb = t / 144, ib = t - (t / 144) * 144;   // valid when bown
  float breg[10];
#pragma unroll
  for (int o = 0; o < 10; ++o) breg[o] = 0.f;

  for (int it = 0; it < 3; ++it) {
    if (it > 0) {
      if (bown) {   // softmax from register b -> cc
        float mx = breg[0];
#pragma unroll
        for (int o = 1; o < 10; ++o) mx = fmaxf(mx, breg[o]);
        float e[10];
        float sum = 0.f;
#pragma unroll
        for (int o = 0; o < 10; ++o) { e[o] = __expf(breg[o] - mx); sum += e[o]; }
        float inv = 1.0f / sum;
#pragma unroll
        for (int o = 0; o < 10; ++o) cc[slb][ib * 10 + o] = e[o] * inv;
      }
      __syncthreads();
      // s partials: per sample, 480 lanes = 6 i-chunks x 80 d-pairs
      if (tl < 480) {
        int ch = tl / 80, dp = tl - ch * 80;
        int o = dp >> 3;
        float a0 = 0.f, a1 = 0.f;
        int i0 = ch * 24;
        for (int i = i0; i < i0 + 24; ++i) {
          float c = cc[sl][i * 10 + o];
          half2_t h = h2(uhh[sl][i * 82 + dp]);
          a0 += c * (float)h[0]; a1 += c * (float)h[1];
        }
        spart[sl][ch][dp * 2] = a0;
        spart[sl][ch][dp * 2 + 1] = a1;
      }
      __syncthreads();
    }
    // fused s-reduce + squash: lanes tl<160 hold s[o=tl/16][d=tl%16]
    if (tl < 160) {
      float s = 0.f;
      if (it == 0) {
#pragma unroll
        for (int c = 0; c < 12; ++c) s += spart[sl][c][tl];
        s *= 0.1f;   // softmax of zeros
      } else {
#pragma unroll
        for (int c = 0; c < 6; ++c) s += spart[sl][c][tl];
      }
      float sq = s * s;
      sq += __shfl_xor(sq, 1);
      sq += __shfl_xor(sq, 2);
      sq += __shfl_xor(sq, 4);
      sq += __shfl_xor(sq, 8);
      float coef = (sq / (1.0f + sq)) / sqrtf(sq + 1e-8f);
      float v = coef * s;
      vv[sl][tl] = v;
      float vn = __shfl_xor(v, 1);
      if ((tl & 1) == 0) vvh[sl][tl >> 1] = pkh2(v, vn);
      if (it == 2 && (tl & 15) == 0)
        out[(b0 + sl) * 10 + (tl >> 4)] = coef * sqrtf(sq);   // pred = ||v||
    }
    __syncthreads();   // vvh ready
    // b-update: register accumulation on owner lanes; no barrier needed after
    if (it < 2 && bown) {
      const uint2* row = (const uint2*)&uhh[slb][ib * 82];
      const uint2* vp = (const uint2*)&vvh[slb][0];
#pragma unroll
      for (int o = 0; o < 10; ++o) {
        uint2 A0 = row[o * 4 + 0], A1 = row[o * 4 + 1];
        uint2 A2 = row[o * 4 + 2], A3 = row[o * 4 + 3];
        uint2 V0 = vp[o * 4 + 0], V1 = vp[o * 4 + 1];
        uint2 V2 = vp[o * 4 + 2], V3 = vp[o * 4 + 3];
        float da = fdot2f(h2(A0.x), h2(V0.x), fdot2f(h2(A0.y), h2(V0.y), 0.f));
        float db = fdot2f(h2(A1.x), h2(V1.x), fdot2f(h2(A1.y), h2(V1.y), 0.f));
        da = fdot2f(h2(A2.x), h2(V2.x), fdot2f(h2(A2.y), h2(V2.y), da));
        db = fdot2f(h2(A3.x), h2(V3.x), fdot2f(h2(A3.y), h2(V3.y), db));
        breg[o] += da + db;
      }
    }
  }
  if (tl < 160) out[B * 10 + (b0 + sl) * 160 + tl] = vv[sl][tl];
}

extern "C" void kernel_launch(void* const* d_in, const int* in_sizes, int n_in,
                              void* d_out, int out_size, void* d_ws, size_t ws_size,
                              hipStream_t stream) {
  const float* in = (const float*)d_in[0];
  const float* w1 = (const float*)d_in[1];
  const float* b1 = (const float*)d_in[2];
  const float* w2 = (const float*)d_in[3];
  const float* b2 = (const float*)d_in[4];
  const float* Wr = (const float*)d_in[5];
  float* out = (float*)d_out;
  int B = in_sizes[0] / 784;
  float* wsf = (float*)d_ws;

  float* u = wsf;                                    // [B][1152] f32
  float* tail = wsf + (size_t)B * 1152;
  _Float16* wBg = (_Float16*)tail;                   // 41472 f16 = 20736 f
  unsigned int* wPr = (unsigned int*)(tail + 20736); // 92160 dw

  packAll<<<360, 256, 0, stream>>>(w2, Wr, wBg, wPr);
  conv_fused<<<B, 320, 0, stream>>>(in, w1, b1, wBg, b2, u);
  routing2_kernel<<<B / 2, 1024, 0, stream>>>(u, wPr, out, B);
}